// Round 4
// baseline (367.584 us; speedup 1.0000x reference)
//
#include <hip/hip_runtime.h>
#include <cstdint>

typedef __attribute__((ext_vector_type(8)))  short bf16x8;   // 8 x bf16 (4 VGPR)
typedef __attribute__((ext_vector_type(16))) float f32x16;   // MFMA 32x32 acc
typedef __attribute__((ext_vector_type(4)))  int   i32x4;

__device__ __forceinline__ unsigned short f2bf(float x) {    // RNE fp32->bf16
  unsigned u = __float_as_uint(x);
  u += 0x7fffu + ((u >> 16) & 1u);
  return (unsigned short)(u >> 16);
}
__device__ __forceinline__ unsigned pk2bf(float lo, float hi) {
#if defined(__has_builtin)
#if __has_builtin(__builtin_amdgcn_cvt_pk_bf16_f32)
  auto v = __builtin_amdgcn_cvt_pk_bf16_f32(lo, hi);
  unsigned u; __builtin_memcpy(&u, &v, 4); return u;
#else
  return ((unsigned)f2bf(hi) << 16) | (unsigned)f2bf(lo);
#endif
#else
  return ((unsigned)f2bf(hi) << 16) | (unsigned)f2bf(lo);
#endif
}
__device__ __forceinline__ float silu_f(float v) {
  return v * __builtin_amdgcn_rcpf(1.0f + __expf(-v));
}

// ---- pack W0/W1/W2 into MFMA B-frag order via LDS transpose (coalesced R+W).
// dest layout: [layer][g(64 cols)][t(32-col tile)][kt][lane][8], K0 padded 134->144.
__global__ void pack_kernel(const float* __restrict__ W0, const float* __restrict__ W1,
                            const float* __restrict__ W2,
                            unsigned short* __restrict__ packW) {
  __shared__ float ldsF[16][257];
  const int s = blockIdx.x, tid = threadIdx.x;
  const float* W; int KT, kmax, base, kt;
  if (s < 9)       { W = W0; KT = 9;  kmax = 134; base = 0;      kt = s; }
  else if (s < 25) { W = W1; KT = 16; kmax = 256; base = 36864;  kt = s - 9; }
  else             { W = W2; KT = 16; kmax = 256; base = 102400; kt = s - 25; }
  const int k0 = kt * 16;
#pragma unroll
  for (int i = 0; i < 8; ++i) {                 // 512 thr x 8 = 16 x 256 floats
    const int idx = i * 512 + tid;
    const int kl = idx >> 8, col = idx & 255;
    const int kg = k0 + kl;
    ldsF[kl][col] = (kg < kmax) ? W[kg * 256 + col] : 0.0f;   // coalesced rows
  }
  __syncthreads();
  const int g = tid >> 7, t = (tid >> 6) & 1, lane = tid & 63;
  const int col = g * 64 + t * 32 + (lane & 31);
  const int kb = 8 * (lane >> 5);
  unsigned u0 = pk2bf(ldsF[kb + 0][col], ldsF[kb + 1][col]);
  unsigned u1 = pk2bf(ldsF[kb + 2][col], ldsF[kb + 3][col]);
  unsigned u2 = pk2bf(ldsF[kb + 4][col], ldsF[kb + 5][col]);
  unsigned u3 = pk2bf(ldsF[kb + 6][col], ldsF[kb + 7][col]);
  unsigned short* dst = packW + base + g * (KT * 1024) + t * (KT * 512) + kt * 512 + lane * 8;
  i32x4 v = { (int)u0, (int)u1, (int)u2, (int)u3 };
  *(i32x4*)dst = v;
}

// ======================================================================
// Decomposition: wave w owns ALL 256 nodes x cols [32w, 32w+32).
// Two node-chunks of 128 with ping-pong acc sets (accA = chunk0, accB = chunk1),
// software-pipelined across the chunk boundary:
//   phase A(L): kloop0(L)  [reads h rows 0..127]   || epi1(L-1) [writes rows 128..255]
//   barrier
//   phase B(L): kloop1(L)  [reads h rows 128..255] || epi0(L)   [writes rows 1..126]
//   deferred nodes 0/127; Bf(L+1) preload; barrier
// Row-disjointness makes each phase race-free; in-place h overwrite is safe.
// B slice in 64 VGPRs (loaded once/layer/wave); h[256][256] bf16 in 128KB LDS,
// 16B-slot XOR swizzle (slot ^= node&31).
// C/D layout: col = lane&31, row = (reg&3) + 8*(reg>>2) + 4*(lane>>5).
// ======================================================================

// one epilogue value v = nt*16 + r of a 4-tile chunk (rk refreshed at r==0)
template <int ELAYER, int ECHUNK>
__device__ __forceinline__ void epi_value(const int v, const f32x16* accEpi, const int q,
                                          float* rk, const float* bsh, const float ext,
                                          const float bias, unsigned short* __restrict__ hbuf,
                                          const int* rowAddr, float& psum) {
  const int nt = v >> 4, r = v & 15;
  if (r == 0) {
#pragma unroll
    for (int k = 0; k < 7; ++k) {                 // internal q-half boundaries (4k+3,4k+4)
      const int lowReg = 4 * (k >> 1) + 3;
      const int upReg  = 4 * ((k + 1) >> 1);
      const float send = (q == (k & 1)) ? accEpi[nt][lowReg] : accEpi[nt][upReg];
      rk[k] = __shfl_xor(send, 32);
    }
  }
  float prev, next;
  if ((r & 3) > 0) prev = accEpi[nt][r - 1];
  else {
    const float pq1 = rk[2 * (r >> 2)];
    float pq0;
    if (r == 0) pq0 = (nt == 0) ? ext : bsh[nt - 1];
    else        pq0 = rk[2 * (r >> 2) - 1];
    prev = q ? pq1 : pq0;
  }
  if ((r & 3) < 3) next = accEpi[nt][r + 1];
  else {
    const float nq0 = rk[2 * (r >> 2)];
    float nq1;
    if (r == 15) nq1 = (nt == 3) ? ext : bsh[nt];
    else         nq1 = rk[2 * (r >> 2) + 1];
    next = q ? nq1 : nq0;
  }
  const float vv = (prev + accEpi[nt][r] + next) * 0.33333333333f + bias;
  const float y = silu_f(vv);
  const bool skip = (ECHUNK == 0) &&
      ((nt == 0 && r == 0 && q == 0) || (nt == 3 && r == 15 && q == 1));
  if constexpr (ELAYER == 2) { if (!skip) psum += y; }
  else if (!skip)
    *(unsigned short*)((char*)hbuf + (ECHUNK * 4 + nt) * 16384 + rowAddr[r]) = f2bf(y);
}

// kloop over one chunk, optionally interleaved 1:1 (in source) with the epilogue
// of the OTHER chunk's acc (branch-free, fully unrolled -> schedulable).
template <int KT, int ELAYER, int ECHUNK, bool DOEPI>
__device__ __forceinline__ void phase(
    const unsigned short* __restrict__ hb,        // kloop read base (incl. chunk offset)
    const bf16x8* Bf, const int q, const int c,
    f32x16* accOut, const f32x16* accEpi,
    const float ext, const float bias,
    unsigned short* __restrict__ hbuf,
    const int* rowAddr, float& psum) {
  float bsh[3], rk[7];
  if constexpr (DOEPI) {
#pragma unroll
    for (int k = 0; k < 3; ++k) {                 // tile k <-> k+1 boundaries
      const float send = q ? accEpi[k][15] : accEpi[k + 1][0];
      bsh[k] = __shfl_xor(send, 32);
    }
  }
#pragma unroll
  for (int nt = 0; nt < 4; ++nt)
#pragma unroll
    for (int j = 0; j < 16; ++j) accOut[nt][j] = 0.f;
#pragma unroll
  for (int kt = 0; kt < KT; ++kt) {
    const unsigned short* base = hb + c * 256 + (((2 * kt + q) ^ c) * 8);
    bf16x8 Af[4];
#pragma unroll
    for (int nt = 0; nt < 4; ++nt)
      Af[nt] = *(const bf16x8*)(base + nt * 8192);
#pragma unroll
    for (int nt = 0; nt < 4; ++nt)
      accOut[nt] = __builtin_amdgcn_mfma_f32_32x32x16_bf16(Af[nt], Bf[kt], accOut[nt], 0, 0, 0);
    if constexpr (DOEPI) {
#pragma unroll
      for (int v = (kt * 64) / KT; v < ((kt + 1) * 64) / KT; ++v)
        epi_value<ELAYER, ECHUNK>(v, accEpi, q, rk, bsh, ext, bias, hbuf, rowAddr, psum);
    }
  }
}

template <int ELAYER, int ECHUNK>
__device__ __forceinline__ void epi_only(const f32x16* accEpi, const int q,
                                         const float ext, const float bias,
                                         unsigned short* __restrict__ hbuf,
                                         const int* rowAddr, float& psum) {
  float bsh[3], rk[7];
#pragma unroll
  for (int k = 0; k < 3; ++k) {
    const float send = q ? accEpi[k][15] : accEpi[k + 1][0];
    bsh[k] = __shfl_xor(send, 32);
  }
#pragma unroll
  for (int v = 0; v < 64; ++v)
    epi_value<ELAYER, ECHUNK>(v, accEpi, q, rk, bsh, ext, bias, hbuf, rowAddr, psum);
}

// deferred nodes 0 (q0) / 127 (q1): need s[255]/s[128] from chunk-1 acc
template <int LAYER>
__device__ __forceinline__ void deferred(const f32x16* accB, const int q,
                                         const float sA, const float sB, const float bias,
                                         unsigned short* __restrict__ hbuf,
                                         const int* rowAddr, float& psum) {
  const float send = q ? accB[3][15] : accB[0][0];
  const float recv = __shfl_xor(send, 32);     // q0: s[255], q1: s[128]
  const float y = silu_f((sA + sB + recv) * 0.33333333333f + bias);
  if constexpr (LAYER == 2) psum += y;
  else {
    const int addr = q ? (3 * 16384 + rowAddr[15]) : rowAddr[0];
    *(unsigned short*)((char*)hbuf + addr) = f2bf(y);
  }
}

// ---------------- main fused kernel: 1 block = 1 graph, 8 waves x 32 cols ----------
__global__ __launch_bounds__(512, 1) void poly_kernel(
    const float* __restrict__ x, const float* __restrict__ t,
    const float* __restrict__ tw, const float* __restrict__ tb,
    const unsigned short* __restrict__ packW,
    const float* __restrict__ B0, const float* __restrict__ B1,
    const float* __restrict__ B2, float* __restrict__ out) {
  __shared__ __align__(16) unsigned short hbuf[65536];  // 128 KiB: h[node][256] bf16, swizzled
  __shared__ __align__(16) unsigned short tmpl[160];    // h0 row template (temb + pads)

  const int tid = threadIdx.x;
  const int w = tid >> 6, lane = tid & 63, q = lane >> 5, c = lane & 31;
  const int b = blockIdx.x;

  // ---- fused time MLP: temb = silu(sinemb(t[b]) @ tw + tb) ----
  {
    float* scr = (float*)hbuf;        // reuse h as f32 scratch (overwritten later)
    if (tid < 128) {
      const float tv = t[b];
      const int i = tid & 63;
      const float f = expf(-0.14619588396823767f * (float)i);  // log(1e4)/63
      const float ang = tv * f;
      scr[tid] = (tid < 64) ? sinf(ang) : cosf(ang);
    }
    __syncthreads();
    {
      const int j = tid & 127, p = tid >> 7;   // 4-way k-split over the block
      float a = 0.f;
#pragma unroll 8
      for (int kk = 0; kk < 32; ++kk) a += scr[p * 32 + kk] * tw[(p * 32 + kk) * 128 + j];
      scr[128 + tid] = a;
    }
    __syncthreads();
    if (tid < 128) {
      const float a = tb[tid] + scr[128 + tid] + scr[256 + tid] + scr[384 + tid] + scr[512 + tid];
      tmpl[6 + tid] = f2bf(silu_f(a));
      if (tid < 6)  tmpl[tid] = 0;
      if (tid < 26) tmpl[134 + tid] = 0;   // pad k 134..159 = 0
    }
    __syncthreads();
  }

  // ---- build h0: [x, y, pe(4), temb(128), 0-pad] per node, swizzled slots 0..17 ----
#pragma unroll
  for (int i = 0; i < 9; ++i) {
    const int task = tid + i * 512;            // 4608 = 256 nodes x 18 slots
    const int node = task & 255, slot = task >> 8;
    i32x4 d = *(const i32x4*)(tmpl + slot * 8);
    if (slot == 0) {                           // per-node coords + cycle pos-enc
      const float2 xy = ((const float2*)x)[b * 256 + node];
      const float th = 0.024543692605870074f * (float)node;   // 2*pi/256
      d.x = (int)pk2bf(xy.x, xy.y);
      d.y = (int)pk2bf(sinf(th), cosf(th));
      d.z = (int)pk2bf(sinf(2.f * th), cosf(2.f * th));
    }
    *(i32x4*)(hbuf + node * 256 + ((slot ^ (node & 31)) * 8)) = d;
  }

  // per-lane h'-write byte addresses (row depends on q; r is compile-time)
  int rowAddr[16];
  const int slotW = 4 * w + (c >> 3), offW = (c & 7) * 2;    // k-index = 32w+c
#pragma unroll
  for (int r = 0; r < 16; ++r) {
    const int row = (r & 3) + 8 * (r >> 2) + 4 * q;
    rowAddr[r] = row * 512 + ((slotW ^ row) * 16) + offW;
  }

  // B slices: wave w <-> group g=w>>1, tile t=w&1 (cols 32w..32w+31)
  const unsigned short* pL0 = packW + (w >> 1) * (9 * 1024) + (w & 1) * (9 * 512);
  const unsigned short* pL1 = packW + 36864 + (w >> 1) * (16 * 1024) + (w & 1) * (16 * 512);
  const unsigned short* pL2 = packW + 102400 + (w >> 1) * (16 * 1024) + (w & 1) * (16 * 512);
  bf16x8 Bf[16];
#pragma unroll
  for (int kt = 0; kt < 9; ++kt) Bf[kt] = *(const bf16x8*)(pL0 + kt * 512 + lane * 8);
  const float bias0 = B0[w * 32 + c], bias1 = B1[w * 32 + c], bias2 = B2[w * 32 + c];
  __syncthreads();   // h0 ready

  f32x16 accA[4], accB[4];
  float psum = 0.f, sA, sB, ext;

  // ---- L0 ----
  phase<9, 0, 0, false>(hbuf, Bf, q, c, accA, accA, 0.f, 0.f, hbuf, rowAddr, psum);
  sA = q ? accA[3][14] : accA[0][0];             // s[126] | s[0]
  sB = q ? accA[3][15] : accA[0][1];             // s[127] | s[1]
  __syncthreads();                               // chunk-0 reads done
  phase<9, 0, 0, true>(hbuf + 32768, Bf, q, c, accB, accA, 0.f, bias0, hbuf, rowAddr, psum);
  deferred<0>(accB, q, sA, sB, bias0, hbuf, rowAddr, psum);
#pragma unroll
  for (int kt = 0; kt < 16; ++kt) Bf[kt] = *(const bf16x8*)(pL1 + kt * 512 + lane * 8);
  __syncthreads();                               // chunk-1 reads done; epi0+deferred visible
  ext = __shfl_xor(q ? sB : sA, 32);             // q0: s[127], q1: s[0]

  // ---- L1 (phase A consumes epi1 of L0) ----
  phase<16, 0, 1, true>(hbuf, Bf, q, c, accA, accB, ext, bias0, hbuf, rowAddr, psum);
  sA = q ? accA[3][14] : accA[0][0];
  sB = q ? accA[3][15] : accA[0][1];
  __syncthreads();
  phase<16, 1, 0, true>(hbuf + 32768, Bf, q, c, accB, accA, 0.f, bias1, hbuf, rowAddr, psum);
  deferred<1>(accB, q, sA, sB, bias1, hbuf, rowAddr, psum);
#pragma unroll
  for (int kt = 0; kt < 16; ++kt) Bf[kt] = *(const bf16x8*)(pL2 + kt * 512 + lane * 8);
  __syncthreads();
  ext = __shfl_xor(q ? sB : sA, 32);

  // ---- L2 (phase A consumes epi1 of L1; epilogues accumulate psum) ----
  phase<16, 1, 1, true>(hbuf, Bf, q, c, accA, accB, ext, bias1, hbuf, rowAddr, psum);
  sA = q ? accA[3][14] : accA[0][0];
  sB = q ? accA[3][15] : accA[0][1];
  __syncthreads();
  phase<16, 2, 0, true>(hbuf + 32768, Bf, q, c, accB, accA, 0.f, bias2, hbuf, rowAddr, psum);
  deferred<2>(accB, q, sA, sB, bias2, hbuf, rowAddr, psum);
  ext = __shfl_xor(q ? sB : sA, 32);
  epi_only<2, 1>(accB, q, ext, bias2, hbuf, rowAddr, psum);   // final epi1(L2) -> psum

  const float s2 = psum + __shfl_xor(psum, 32);
  if (q == 0) out[b * 256 + w * 32 + c] = s2 * (1.0f / 256.0f);
}

// ---------------- launch ----------------
extern "C" void kernel_launch(void* const* d_in, const int* in_sizes, int n_in,
                              void* d_out, int out_size, void* d_ws, size_t ws_size,
                              hipStream_t stream) {
  const float* x  = (const float*)d_in[0];
  const float* t  = (const float*)d_in[1];
  const float* tw = (const float*)d_in[2];
  const float* tb = (const float*)d_in[3];
  const float* W0 = (const float*)d_in[4];
  const float* b0 = (const float*)d_in[5];
  const float* W1 = (const float*)d_in[6];
  const float* b1 = (const float*)d_in[7];
  const float* W2 = (const float*)d_in[8];
  const float* b2 = (const float*)d_in[9];

  unsigned short* packW = (unsigned short*)d_ws;   // 167936 shorts
  float* out = (float*)d_out;

  pack_kernel<<<41, 512, 0, stream>>>(W0, W1, W2, packW);
  poly_kernel<<<1024, 512, 0, stream>>>(x, t, tw, tb, packW, b0, b1, b2, out);
}

// Round 5
// 196.576 us; speedup vs baseline: 1.8699x; 1.8699x over previous
//
#include <hip/hip_runtime.h>
#include <cstdint>

typedef __attribute__((ext_vector_type(8)))  short bf16x8;   // 8 x bf16 (4 VGPR)
typedef __attribute__((ext_vector_type(16))) float f32x16;   // MFMA 32x32 acc
typedef __attribute__((ext_vector_type(4)))  int   i32x4;

__device__ __forceinline__ unsigned short f2bf(float x) {    // RNE fp32->bf16
  unsigned u = __float_as_uint(x);
  u += 0x7fffu + ((u >> 16) & 1u);
  return (unsigned short)(u >> 16);
}
__device__ __forceinline__ unsigned pk2bf(float lo, float hi) {
#if defined(__has_builtin)
#if __has_builtin(__builtin_amdgcn_cvt_pk_bf16_f32)
  auto v = __builtin_amdgcn_cvt_pk_bf16_f32(lo, hi);
  unsigned u; __builtin_memcpy(&u, &v, 4); return u;
#else
  return ((unsigned)f2bf(hi) << 16) | (unsigned)f2bf(lo);
#endif
#else
  return ((unsigned)f2bf(hi) << 16) | (unsigned)f2bf(lo);
#endif
}
__device__ __forceinline__ float silu_f(float v) {
  return v * __builtin_amdgcn_rcpf(1.0f + __expf(-v));
}

// ---- pack W0/W1/W2 into MFMA B-frag order via LDS transpose (coalesced R+W).
// dest layout: [layer][g(64 cols)][t(32-col tile)][kt][lane][8], K0 padded 134->144.
__global__ void pack_kernel(const float* __restrict__ W0, const float* __restrict__ W1,
                            const float* __restrict__ W2,
                            unsigned short* __restrict__ packW) {
  __shared__ float ldsF[16][257];
  const int s = blockIdx.x, tid = threadIdx.x;
  const float* W; int KT, kmax, base, kt;
  if (s < 9)       { W = W0; KT = 9;  kmax = 134; base = 0;      kt = s; }
  else if (s < 25) { W = W1; KT = 16; kmax = 256; base = 36864;  kt = s - 9; }
  else             { W = W2; KT = 16; kmax = 256; base = 102400; kt = s - 25; }
  const int k0 = kt * 16;
#pragma unroll
  for (int i = 0; i < 8; ++i) {                 // 512 thr x 8 = 16 x 256 floats
    const int idx = i * 512 + tid;
    const int kl = idx >> 8, col = idx & 255;
    const int kg = k0 + kl;
    ldsF[kl][col] = (kg < kmax) ? W[kg * 256 + col] : 0.0f;   // coalesced rows
  }
  __syncthreads();
  const int g = tid >> 7, t = (tid >> 6) & 1, lane = tid & 63;
  const int col = g * 64 + t * 32 + (lane & 31);
  const int kb = 8 * (lane >> 5);
  unsigned u0 = pk2bf(ldsF[kb + 0][col], ldsF[kb + 1][col]);
  unsigned u1 = pk2bf(ldsF[kb + 2][col], ldsF[kb + 3][col]);
  unsigned u2 = pk2bf(ldsF[kb + 4][col], ldsF[kb + 5][col]);
  unsigned u3 = pk2bf(ldsF[kb + 6][col], ldsF[kb + 7][col]);
  unsigned short* dst = packW + base + g * (KT * 1024) + t * (KT * 512) + kt * 512 + lane * 8;
  i32x4 v = { (int)u0, (int)u1, (int)u2, (int)u3 };
  *(i32x4*)dst = v;
}

// ======================================================================
// Wave w owns ALL 256 nodes x cols [32w,32w+32). Node->A-row permutation
// (sig) makes each lane's 16 acc regs hold 16 CONSECUTIVE nodes:
//   lane (q,c), tile nt, reg r  <->  node 32nt + 16q + r
//   (A/C row m within tile <-> node_local sig(m) = (m&3)+4*((m>>3)&3)+16*((m>>2)&1);
//    inverse row(n) = (n&3)+8*((n>>2)&3)+4*((n>>4)&1))
// => cyclic +-1 aggregation is in-register for r=1..14; only r==0/r==15 need
//    one shfl_xor(32) each (3 shuffles per 2-tile sub).
// Pipeline: 4 subs of 2 tiles, ping-pong acc sets (64 VGPR total), each kloop
// interleaved 1:1 in source with the epilogue of the previous sub:
//   B(i+1): K(s_{i+1}) [reads h rows 64(i+1)..] || epi(s_i) [writes rows 64i..]
// Row-disjoint -> one barrier per block. Edge nodes 0/63/127/191 via saved
// scalars + deferred fixups (no extra barriers). L2 epilogues only pool ->
// no LDS writes -> inner barriers dropped.
// B slice resident in 64 VGPRs; h[256][256] bf16 in 128KB LDS, 16B-slot XOR
// swizzle (slot ^= row&31). Total reg demand ~190 <= 256 cap (2 waves/SIMD).
// ======================================================================

// one epilogue value v = t*16 + r (t,r compile-time after unroll)
template <int ELAYER, bool DF, bool DL>
__device__ __forceinline__ void epi_v(
    const int v, const f32x16* accEpi, const int q,
    const float recvI0, const float recvI1, const float recvX,
    const float extP, const float extN, const float bias,
    const int epiSub, unsigned short* __restrict__ hbuf,
    const int* rowAddr, float& psum) {
  const int t = v >> 4, r = v & 15;
  float prev, next;
  if (r > 0) prev = accEpi[t][r - 1];
  else       prev = q ? (t ? recvI1 : recvI0) : (t ? recvX : extP);
  if (r < 15) next = accEpi[t][r + 1];
  else        next = q ? (t ? extN : recvX) : (t ? recvI1 : recvI0);
  const float vv = (prev + accEpi[t][r] + next) * 0.33333333333f + bias;
  const float y = silu_f(vv);
  const bool commit = !((DF && t == 0 && r == 0 && q == 0) ||
                        (DL && t == 1 && r == 15 && q == 1));
  if constexpr (ELAYER == 2) { if (commit) psum += y; }
  else if (commit)
    *(unsigned short*)((char*)hbuf + (2 * epiSub + t) * 16384 + rowAddr[r]) = f2bf(y);
}

// fused block: kloop over 2 tiles of readSub, interleaved with epi of epiSub
template <int KT, int ELAYER, bool DOEPI, bool DF, bool DL>
__device__ __forceinline__ void fblock(
    unsigned short* __restrict__ hbuf, const int readSub, const int epiSub,
    const bf16x8* Bf, const int q, const int c,
    f32x16* accOut, const f32x16* accEpi,
    const float extP, const float extN, const float bias,
    const int* rowAddr, float& psum) {
  float recvI0 = 0.f, recvI1 = 0.f, recvX = 0.f;
  if constexpr (DOEPI) {
    recvI0 = __shfl_xor(q ? accEpi[0][0]  : accEpi[0][15], 32);
    recvI1 = __shfl_xor(q ? accEpi[1][0]  : accEpi[1][15], 32);
    recvX  = __shfl_xor(q ? accEpi[0][15] : accEpi[1][0],  32);
  }
#pragma unroll
  for (int t2 = 0; t2 < 2; ++t2)
#pragma unroll
    for (int j = 0; j < 16; ++j) accOut[t2][j] = 0.f;
  const unsigned short* rb = hbuf + readSub * 16384 + c * 256;
#pragma unroll
  for (int kt = 0; kt < KT; ++kt) {
    const unsigned short* base = rb + (((2 * kt + q) ^ c) * 8);
    const bf16x8 a0 = *(const bf16x8*)(base);
    const bf16x8 a1 = *(const bf16x8*)(base + 8192);
    accOut[0] = __builtin_amdgcn_mfma_f32_32x32x16_bf16(a0, Bf[kt], accOut[0], 0, 0, 0);
    accOut[1] = __builtin_amdgcn_mfma_f32_32x32x16_bf16(a1, Bf[kt], accOut[1], 0, 0, 0);
    if constexpr (DOEPI) {
#pragma unroll
      for (int v = (kt * 32) / KT; v < ((kt + 1) * 32) / KT; ++v)
        epi_v<ELAYER, DF, DL>(v, accEpi, q, recvI0, recvI1, recvX, extP, extN,
                              bias, epiSub, hbuf, rowAddr, psum);
    }
  }
}

template <int ELAYER>
__device__ __forceinline__ void epi_only(
    const f32x16* accEpi, const int q, const float extP, const float extN,
    const float bias, const int epiSub, unsigned short* __restrict__ hbuf,
    const int* rowAddr, float& psum) {
  const float recvI0 = __shfl_xor(q ? accEpi[0][0]  : accEpi[0][15], 32);
  const float recvI1 = __shfl_xor(q ? accEpi[1][0]  : accEpi[1][15], 32);
  const float recvX  = __shfl_xor(q ? accEpi[0][15] : accEpi[1][0],  32);
#pragma unroll
  for (int v = 0; v < 32; ++v)
    epi_v<ELAYER, false, false>(v, accEpi, q, recvI0, recvI1, recvX, extP, extN,
                                bias, epiSub, hbuf, rowAddr, psum);
}

// node 64e+63 (q1 lanes): prev/cur in accEpi[1][14..15], next = new sub's node 64e+64
template <int ELAYER>
__device__ __forceinline__ void defer_last(
    const f32x16* accEpi, const float accNew00, const int epiSub,
    const float bias, const int q, unsigned short* __restrict__ hbuf,
    const int* rowAddr, float& psum) {
  const float recv = __shfl_xor(q ? 0.f : accNew00, 32);   // q1 <- s[64e+64]
  const float y = silu_f((accEpi[1][14] + accEpi[1][15] + recv) * 0.33333333333f + bias);
  if (q) {
    if constexpr (ELAYER == 2) psum += y;
    else *(unsigned short*)((char*)hbuf + (2 * epiSub + 1) * 16384 + rowAddr[15]) = f2bf(y);
  }
}

// node 0 (q0 lanes): prev = s[255] (from s3 acc, q1 send), cur/next = saved s[0],s[1]
template <int ELAYER>
__device__ __forceinline__ void fix_node0(
    const float s255src, const float sv0, const float sv1,
    const float bias, const int q, unsigned short* __restrict__ hbuf,
    const int* rowAddr, float& psum) {
  const float recv = __shfl_xor(q ? s255src : 0.f, 32);    // q0 <- s[255]
  const float y = silu_f((recv + sv0 + sv1) * 0.33333333333f + bias);
  if (!q) {
    if constexpr (ELAYER == 2) psum += y;
    else *(unsigned short*)((char*)hbuf + rowAddr[0]) = f2bf(y);
  }
}

// ---------------- main fused kernel: 1 block = 1 graph, 8 waves x 32 cols ----------
__global__ __launch_bounds__(512, 1) void poly_kernel(
    const float* __restrict__ x, const float* __restrict__ t,
    const float* __restrict__ tw, const float* __restrict__ tb,
    const unsigned short* __restrict__ packW,
    const float* __restrict__ B0, const float* __restrict__ B1,
    const float* __restrict__ B2, float* __restrict__ out) {
  __shared__ __align__(16) unsigned short hbuf[65536];  // 128 KiB: h[row][256] bf16, swizzled
  __shared__ __align__(16) unsigned short tmpl[160];    // h0 row template (temb + pads)

  const int tid = threadIdx.x;
  const int w = tid >> 6, lane = tid & 63, q = lane >> 5, c = lane & 31;
  const int b = blockIdx.x;

  // ---- fused time MLP: temb = silu(sinemb(t[b]) @ tw + tb) ----
  {
    float* scr = (float*)hbuf;        // reuse h as f32 scratch (overwritten later)
    if (tid < 128) {
      const float tv = t[b];
      const int i = tid & 63;
      const float f = expf(-0.14619588396823767f * (float)i);  // log(1e4)/63
      const float ang = tv * f;
      scr[tid] = (tid < 64) ? sinf(ang) : cosf(ang);
    }
    __syncthreads();
    {
      const int j = tid & 127, p = tid >> 7;   // 4-way k-split over the block
      float a = 0.f;
#pragma unroll 8
      for (int kk = 0; kk < 32; ++kk) a += scr[p * 32 + kk] * tw[(p * 32 + kk) * 128 + j];
      scr[128 + tid] = a;
    }
    __syncthreads();
    if (tid < 128) {
      const float a = tb[tid] + scr[128 + tid] + scr[256 + tid] + scr[384 + tid] + scr[512 + tid];
      tmpl[6 + tid] = f2bf(silu_f(a));
      if (tid < 6)  tmpl[tid] = 0;
      if (tid < 26) tmpl[134 + tid] = 0;   // pad k 134..159 = 0
    }
    __syncthreads();
  }

  // ---- build h0 with node->row permutation, swizzled 16B slots ----
#pragma unroll
  for (int i = 0; i < 9; ++i) {
    const int task = tid + i * 512;            // 4608 = 256 nodes x 18 slots
    const int node = task & 255, slot = task >> 8;
    i32x4 d = *(const i32x4*)(tmpl + slot * 8);
    if (slot == 0) {                           // per-node coords + cycle pos-enc
      const float2 xy = ((const float2*)x)[b * 256 + node];
      const float th = 0.024543692605870074f * (float)node;   // 2*pi/256
      d.x = (int)pk2bf(xy.x, xy.y);
      d.y = (int)pk2bf(sinf(th), cosf(th));
      d.z = (int)pk2bf(sinf(2.f * th), cosf(2.f * th));
    }
    const int m = (node & 3) + 8 * ((node >> 2) & 3) + 4 * ((node >> 4) & 1);
    const int R = (node & ~31) | m;            // permuted LDS row
    *(i32x4*)(hbuf + R * 256 + ((slot ^ m) * 8)) = d;
  }

  // per-lane h'-write byte addresses (row within tile; r compile-time)
  int rowAddr[16];
  const int slotW = 4 * w + (c >> 3), offW = (c & 7) * 2;    // k-index = 32w+c
#pragma unroll
  for (int r = 0; r < 16; ++r) {
    const int row = (r & 3) + 8 * (r >> 2) + 4 * q;
    rowAddr[r] = row * 512 + ((slotW ^ row) * 16) + offW;
  }

  // B slices: wave w <-> group g=w>>1, tile t=w&1 (cols 32w..32w+31)
  const unsigned short* pL0 = packW + (w >> 1) * (9 * 1024) + (w & 1) * (9 * 512);
  const unsigned short* pL1 = packW + 36864 + (w >> 1) * (16 * 1024) + (w & 1) * (16 * 512);
  const unsigned short* pL2 = packW + 102400 + (w >> 1) * (16 * 1024) + (w & 1) * (16 * 512);
  bf16x8 Bf[16];
#pragma unroll
  for (int kt = 0; kt < 9; ++kt) Bf[kt] = *(const bf16x8*)(pL0 + kt * 512 + lane * 8);
  const float bias0 = B0[w * 32 + c], bias1 = B1[w * 32 + c], bias2 = B2[w * 32 + c];
  __syncthreads();   // h0 ready

  f32x16 accA[2], accB[2];
  float psum = 0.f, sv0, sv1, extP, extN;

  // ================= L0 =================
  fblock<9, 0, false, false, false>(hbuf, 0, 0, Bf, q, c, accA, accA, 0.f, 0.f, 0.f, rowAddr, psum);
  sv0 = accA[0][0]; sv1 = accA[0][1];                       // s[0], s[1] (q0)
  __syncthreads();
  fblock<9, 0, true, true, true>(hbuf, 1, 0, Bf, q, c, accB, accA, 0.f, 0.f, bias0, rowAddr, psum);
  defer_last<0>(accA, accB[0][0], 0, bias0, q, hbuf, rowAddr, psum);       // node 63
  extP = __shfl_xor(q ? accA[1][15] : 0.f, 32);                            // s[63] -> q0
  __syncthreads();
  fblock<9, 0, true, false, true>(hbuf, 2, 1, Bf, q, c, accA, accB, extP, 0.f, bias0, rowAddr, psum);
  defer_last<0>(accB, accA[0][0], 1, bias0, q, hbuf, rowAddr, psum);       // node 127
  extP = __shfl_xor(q ? accB[1][15] : 0.f, 32);                            // s[127]
  __syncthreads();
  fblock<9, 0, true, false, true>(hbuf, 3, 2, Bf, q, c, accB, accA, extP, 0.f, bias0, rowAddr, psum);
  defer_last<0>(accA, accB[0][0], 2, bias0, q, hbuf, rowAddr, psum);       // node 191
  fix_node0<0>(accB[1][15], sv0, sv1, bias0, q, hbuf, rowAddr, psum);      // node 0
  extP = __shfl_xor(q ? accA[1][15] : 0.f, 32);                            // s[191]
  extN = __shfl_xor(q ? 0.f : sv0, 32);                                    // s[0] -> q1
#pragma unroll
  for (int kt = 0; kt < 16; ++kt) Bf[kt] = *(const bf16x8*)(pL1 + kt * 512 + lane * 8);
  __syncthreads();

  // ================= L1 =================
  fblock<16, 0, true, false, false>(hbuf, 0, 3, Bf, q, c, accA, accB, extP, extN, bias0, rowAddr, psum);
  sv0 = accA[0][0]; sv1 = accA[0][1];
  __syncthreads();
  fblock<16, 1, true, true, true>(hbuf, 1, 0, Bf, q, c, accB, accA, 0.f, 0.f, bias1, rowAddr, psum);
  defer_last<1>(accA, accB[0][0], 0, bias1, q, hbuf, rowAddr, psum);
  extP = __shfl_xor(q ? accA[1][15] : 0.f, 32);
  __syncthreads();
  fblock<16, 1, true, false, true>(hbuf, 2, 1, Bf, q, c, accA, accB, extP, 0.f, bias1, rowAddr, psum);
  defer_last<1>(accB, accA[0][0], 1, bias1, q, hbuf, rowAddr, psum);
  extP = __shfl_xor(q ? accB[1][15] : 0.f, 32);
  __syncthreads();
  fblock<16, 1, true, false, true>(hbuf, 3, 2, Bf, q, c, accB, accA, extP, 0.f, bias1, rowAddr, psum);
  defer_last<1>(accA, accB[0][0], 2, bias1, q, hbuf, rowAddr, psum);
  fix_node0<1>(accB[1][15], sv0, sv1, bias1, q, hbuf, rowAddr, psum);
  extP = __shfl_xor(q ? accA[1][15] : 0.f, 32);
  extN = __shfl_xor(q ? 0.f : sv0, 32);
#pragma unroll
  for (int kt = 0; kt < 16; ++kt) Bf[kt] = *(const bf16x8*)(pL2 + kt * 512 + lane * 8);
  __syncthreads();

  // ================= L2 (pool only; no LDS writes -> fewer barriers) =================
  fblock<16, 1, true, false, false>(hbuf, 0, 3, Bf, q, c, accA, accB, extP, extN, bias1, rowAddr, psum);
  sv0 = accA[0][0]; sv1 = accA[0][1];
  __syncthreads();                              // epi(s3,L1) wrote rows 192..255
  fblock<16, 2, true, true, true>(hbuf, 1, 0, Bf, q, c, accB, accA, 0.f, 0.f, bias2, rowAddr, psum);
  defer_last<2>(accA, accB[0][0], 0, bias2, q, hbuf, rowAddr, psum);
  extP = __shfl_xor(q ? accA[1][15] : 0.f, 32);
  fblock<16, 2, true, false, true>(hbuf, 2, 1, Bf, q, c, accA, accB, extP, 0.f, bias2, rowAddr, psum);
  defer_last<2>(accB, accA[0][0], 1, bias2, q, hbuf, rowAddr, psum);
  extP = __shfl_xor(q ? accB[1][15] : 0.f, 32);
  fblock<16, 2, true, false, true>(hbuf, 3, 2, Bf, q, c, accB, accA, extP, 0.f, bias2, rowAddr, psum);
  defer_last<2>(accA, accB[0][0], 2, bias2, q, hbuf, rowAddr, psum);
  fix_node0<2>(accB[1][15], sv0, sv1, bias2, q, hbuf, rowAddr, psum);
  extP = __shfl_xor(q ? accA[1][15] : 0.f, 32);
  extN = __shfl_xor(q ? 0.f : sv0, 32);
  epi_only<2>(accB, q, extP, extN, bias2, 3, hbuf, rowAddr, psum);

  const float s2 = psum + __shfl_xor(psum, 32);
  if (q == 0) out[b * 256 + w * 32 + c] = s2 * (1.0f / 256.0f);
}

// ---------------- launch ----------------
extern "C" void kernel_launch(void* const* d_in, const int* in_sizes, int n_in,
                              void* d_out, int out_size, void* d_ws, size_t ws_size,
                              hipStream_t stream) {
  const float* x  = (const float*)d_in[0];
  const float* t  = (const float*)d_in[1];
  const float* tw = (const float*)d_in[2];
  const float* tb = (const float*)d_in[3];
  const float* W0 = (const float*)d_in[4];
  const float* b0 = (const float*)d_in[5];
  const float* W1 = (const float*)d_in[6];
  const float* b1 = (const float*)d_in[7];
  const float* W2 = (const float*)d_in[8];
  const float* b2 = (const float*)d_in[9];

  unsigned short* packW = (unsigned short*)d_ws;   // 167936 shorts
  float* out = (float*)d_out;

  pack_kernel<<<41, 512, 0, stream>>>(W0, W1, W2, packW);
  poly_kernel<<<1024, 512, 0, stream>>>(x, t, tw, tb, packW, b0, b1, b2, out);
}

// Round 6
// 186.342 us; speedup vs baseline: 1.9726x; 1.0549x over previous
//
#include <hip/hip_runtime.h>
#include <cstdint>

typedef __attribute__((ext_vector_type(8)))  short bf16x8;   // 8 x bf16 (4 VGPR)
typedef __attribute__((ext_vector_type(16))) float f32x16;   // MFMA 32x32 acc
typedef __attribute__((ext_vector_type(4)))  int   i32x4;

__device__ __forceinline__ unsigned short f2bf(float x) {    // RNE fp32->bf16
  unsigned u = __float_as_uint(x);
  u += 0x7fffu + ((u >> 16) & 1u);
  return (unsigned short)(u >> 16);
}
__device__ __forceinline__ unsigned pk2bf(float lo, float hi) {
#if defined(__has_builtin)
#if __has_builtin(__builtin_amdgcn_cvt_pk_bf16_f32)
  auto v = __builtin_amdgcn_cvt_pk_bf16_f32(lo, hi);
  unsigned u; __builtin_memcpy(&u, &v, 4); return u;
#else
  return ((unsigned)f2bf(hi) << 16) | (unsigned)f2bf(lo);
#endif
#else
  return ((unsigned)f2bf(hi) << 16) | (unsigned)f2bf(lo);
#endif
}
__device__ __forceinline__ float silu_f(float v) {
  return v * __builtin_amdgcn_rcpf(1.0f + __expf(-v));
}

// half-exchange without the LDS pipe: lanes 0-31 receive A from lane+32,
// lanes 32-63 receive B from lane-32  (== __shfl_xor(q ? A : B, 32)).
__device__ __forceinline__ float xchg32(float A, float B, int q) {
#if defined(__has_builtin)
#if __has_builtin(__builtin_amdgcn_permlane32_swap)
  auto r = __builtin_amdgcn_permlane32_swap(__float_as_uint(A), __float_as_uint(B),
                                            false, false);
  // r[0] = {A.lo, B.lo}, r[1] = {A.hi, B.hi} (lane blocks)
  return __uint_as_float(q ? r[0] : r[1]);
#else
  return __shfl_xor(q ? A : B, 32);
#endif
#else
  return __shfl_xor(q ? A : B, 32);
#endif
}

// ---- pack W/3 into MFMA B-frag order via LDS transpose (coalesced R+W).
// 1/3 aggregation factor folded into the weights; bias folded into acc init.
// dest layout: [layer][g(64 cols)][t(32-col tile)][kt][lane][8], K0 padded 134->144.
__global__ void pack_kernel(const float* __restrict__ W0, const float* __restrict__ W1,
                            const float* __restrict__ W2,
                            unsigned short* __restrict__ packW) {
  __shared__ float ldsF[16][257];
  const int s = blockIdx.x, tid = threadIdx.x;
  const float* W; int KT, kmax, base, kt;
  if (s < 9)       { W = W0; KT = 9;  kmax = 134; base = 0;      kt = s; }
  else if (s < 25) { W = W1; KT = 16; kmax = 256; base = 36864;  kt = s - 9; }
  else             { W = W2; KT = 16; kmax = 256; base = 102400; kt = s - 25; }
  const int k0 = kt * 16;
#pragma unroll
  for (int i = 0; i < 8; ++i) {                 // 512 thr x 8 = 16 x 256 floats
    const int idx = i * 512 + tid;
    const int kl = idx >> 8, col = idx & 255;
    const int kg = k0 + kl;
    ldsF[kl][col] = (kg < kmax) ? W[kg * 256 + col] * 0.33333334f : 0.0f;
  }
  __syncthreads();
  const int g = tid >> 7, t = (tid >> 6) & 1, lane = tid & 63;
  const int col = g * 64 + t * 32 + (lane & 31);
  const int kb = 8 * (lane >> 5);
  unsigned u0 = pk2bf(ldsF[kb + 0][col], ldsF[kb + 1][col]);
  unsigned u1 = pk2bf(ldsF[kb + 2][col], ldsF[kb + 3][col]);
  unsigned u2 = pk2bf(ldsF[kb + 4][col], ldsF[kb + 5][col]);
  unsigned u3 = pk2bf(ldsF[kb + 6][col], ldsF[kb + 7][col]);
  unsigned short* dst = packW + base + g * (KT * 1024) + t * (KT * 512) + kt * 512 + lane * 8;
  i32x4 v = { (int)u0, (int)u1, (int)u2, (int)u3 };
  *(i32x4*)dst = v;
}

// ======================================================================
// Wave w owns ALL 256 nodes x cols [32w,32w+32). Node->A-row permutation puts
// 16 CONSECUTIVE nodes in each lane's acc regs: node 32nt + 16q + r.
// s~[n] = (h W/3)[n] + bias/3 (bias via acc init) => y[n] = silu(s~[n-1]+s~[n]+s~[n+1]).
// 4 subs of 2 tiles, ping-pong acc, kloop interleaved 1:1 with prev-sub epilogue.
// Boundary exchange via v_permlane32_swap (VALU, no LDS pipe).
// h' stores via v_cvt_pk_bf16_f32 pairs. h[256][256] bf16 in 128KB LDS,
// 16B-slot XOR swizzle (slot ^= row&31). B slice resident in 64 VGPRs.
// ======================================================================

// one epilogue PAIR p (values r=2(p&7), +1 of tile t=p>>3)
template <int ELAYER, bool DF, bool DL>
__device__ __forceinline__ void epi_pair(
    const int p, const f32x16* accEpi, const int q,
    const float recvI0, const float recvI1, const float recvX,
    const float extP, const float extN,
    const int epiSub, unsigned short* __restrict__ hbuf,
    const int* rowAddr, float& psum) {
  const int t = p >> 3, rp = (p & 7) * 2;
  float y0, y1;
  {
    const int r = rp;
    float prev;
    if (r > 0) prev = accEpi[t][r - 1];
    else       prev = q ? (t ? recvI1 : recvI0) : (t ? recvX : extP);
    y0 = silu_f(prev + accEpi[t][r] + accEpi[t][r + 1]);
  }
  {
    const int r = rp + 1;
    float next;
    if (r < 15) next = accEpi[t][r + 1];
    else        next = q ? (t ? extN : recvX) : (t ? recvI1 : recvI0);
    y1 = silu_f(accEpi[t][r - 1] + accEpi[t][r] + next);
  }
  const bool c0 = !(DF && t == 0 && rp == 0 && q == 0);
  const bool c1 = !(DL && t == 1 && rp == 14 && q == 1);
  if constexpr (ELAYER == 2) {
    if (c0) psum += y0;
    if (c1) psum += y1;
  } else {
    const unsigned u = pk2bf(y0, y1);
    char* bp = (char*)hbuf + (2 * epiSub + t) * 16384;
    if (c0) *(unsigned short*)(bp + rowAddr[rp])     = (unsigned short)u;
    if (c1) *(unsigned short*)(bp + rowAddr[rp + 1]) = (unsigned short)(u >> 16);
  }
}

// fused block: kloop over 2 tiles of readSub (acc init = bias/3), interleaved
// with the epilogue pairs of epiSub (prev sub), branch-free and unrolled.
template <int KT, int ELAYER, bool DOEPI, bool DF, bool DL>
__device__ __forceinline__ void fblock(
    unsigned short* __restrict__ hbuf, const int readSub, const int epiSub,
    const bf16x8* Bf, const int q, const int c, const float bias3,
    f32x16* accOut, const f32x16* accEpi,
    const float extP, const float extN,
    const int* rowAddr, float& psum) {
  float recvI0 = 0.f, recvI1 = 0.f, recvX = 0.f;
  if constexpr (DOEPI) {
    recvI0 = xchg32(accEpi[0][0],  accEpi[0][15], q);
    recvI1 = xchg32(accEpi[1][0],  accEpi[1][15], q);
    recvX  = xchg32(accEpi[0][15], accEpi[1][0],  q);
  }
#pragma unroll
  for (int t2 = 0; t2 < 2; ++t2)
#pragma unroll
    for (int j = 0; j < 16; ++j) accOut[t2][j] = bias3;
  const unsigned short* rb = hbuf + readSub * 16384 + c * 256;
#pragma unroll
  for (int kt = 0; kt < KT; ++kt) {
    const unsigned short* base = rb + (((2 * kt + q) ^ c) * 8);
    const bf16x8 a0 = *(const bf16x8*)(base);
    const bf16x8 a1 = *(const bf16x8*)(base + 8192);
    accOut[0] = __builtin_amdgcn_mfma_f32_32x32x16_bf16(a0, Bf[kt], accOut[0], 0, 0, 0);
    accOut[1] = __builtin_amdgcn_mfma_f32_32x32x16_bf16(a1, Bf[kt], accOut[1], 0, 0, 0);
    if constexpr (DOEPI) {
#pragma unroll
      for (int p = (kt * 16) / KT; p < ((kt + 1) * 16) / KT; ++p)
        epi_pair<ELAYER, DF, DL>(p, accEpi, q, recvI0, recvI1, recvX, extP, extN,
                                 epiSub, hbuf, rowAddr, psum);
    }
  }
}

template <int ELAYER>
__device__ __forceinline__ void epi_only(
    const f32x16* accEpi, const int q, const float extP, const float extN,
    const int epiSub, unsigned short* __restrict__ hbuf,
    const int* rowAddr, float& psum) {
  const float recvI0 = xchg32(accEpi[0][0],  accEpi[0][15], q);
  const float recvI1 = xchg32(accEpi[1][0],  accEpi[1][15], q);
  const float recvX  = xchg32(accEpi[0][15], accEpi[1][0],  q);
#pragma unroll
  for (int p = 0; p < 16; ++p)
    epi_pair<ELAYER, false, false>(p, accEpi, q, recvI0, recvI1, recvX, extP, extN,
                                   epiSub, hbuf, rowAddr, psum);
}

// node 64e+63 (q1 lanes): prev/cur in accEpi[1][14..15], next = new sub's node 64e+64
template <int ELAYER>
__device__ __forceinline__ void defer_last(
    const f32x16* accEpi, const float accNew00, const int epiSub,
    const int q, unsigned short* __restrict__ hbuf,
    const int* rowAddr, float& psum) {
  const float recv = xchg32(0.f, accNew00, q);   // q1 <- s~[64e+64]
  const float y = silu_f(accEpi[1][14] + accEpi[1][15] + recv);
  if (q) {
    if constexpr (ELAYER == 2) psum += y;
    else *(unsigned short*)((char*)hbuf + (2 * epiSub + 1) * 16384 + rowAddr[15]) = f2bf(y);
  }
}

// node 0 (q0 lanes): prev = s~[255], cur/next = saved s~[0], s~[1]
template <int ELAYER>
__device__ __forceinline__ void fix_node0(
    const float s255src, const float sv0, const float sv1,
    const int q, unsigned short* __restrict__ hbuf,
    const int* rowAddr, float& psum) {
  const float recv = xchg32(s255src, 0.f, q);    // q0 <- s~[255]
  const float y = silu_f(recv + sv0 + sv1);
  if (!q) {
    if constexpr (ELAYER == 2) psum += y;
    else *(unsigned short*)((char*)hbuf + rowAddr[0]) = f2bf(y);
  }
}

// ---------------- main fused kernel: 1 block = 1 graph, 8 waves x 32 cols ----------
__global__ __launch_bounds__(512, 1) void poly_kernel(
    const float* __restrict__ x, const float* __restrict__ t,
    const float* __restrict__ tw, const float* __restrict__ tb,
    const unsigned short* __restrict__ packW,
    const float* __restrict__ B0, const float* __restrict__ B1,
    const float* __restrict__ B2, float* __restrict__ out) {
  __shared__ __align__(16) unsigned short hbuf[65536];  // 128 KiB: h[row][256] bf16, swizzled
  __shared__ __align__(16) unsigned short tmpl[160];    // h0 row template (temb + pads)

  const int tid = threadIdx.x;
  const int w = tid >> 6, lane = tid & 63, q = lane >> 5, c = lane & 31;
  const int b = blockIdx.x;

  // ---- fused time MLP: temb = silu(sinemb(t[b]) @ tw + tb) ----
  {
    float* scr = (float*)hbuf;        // reuse h as f32 scratch (overwritten later)
    if (tid < 128) {
      const float tv = t[b];
      const int i = tid & 63;
      const float f = expf(-0.14619588396823767f * (float)i);  // log(1e4)/63
      const float ang = tv * f;
      scr[tid] = (tid < 64) ? sinf(ang) : cosf(ang);
    }
    __syncthreads();
    {
      const int j = tid & 127, p = tid >> 7;   // 4-way k-split over the block
      float a = 0.f;
#pragma unroll 8
      for (int kk = 0; kk < 32; ++kk) a += scr[p * 32 + kk] * tw[(p * 32 + kk) * 128 + j];
      scr[128 + tid] = a;
    }
    __syncthreads();
    if (tid < 128) {
      const float a = tb[tid] + scr[128 + tid] + scr[256 + tid] + scr[384 + tid] + scr[512 + tid];
      tmpl[6 + tid] = f2bf(silu_f(a));
      if (tid < 6)  tmpl[tid] = 0;
      if (tid < 26) tmpl[134 + tid] = 0;   // pad k 134..159 = 0
    }
    __syncthreads();
  }

  // ---- build h0 with node->row permutation, swizzled 16B slots ----
#pragma unroll
  for (int i = 0; i < 9; ++i) {
    const int task = tid + i * 512;            // 4608 = 256 nodes x 18 slots
    const int node = task & 255, slot = task >> 8;
    i32x4 d = *(const i32x4*)(tmpl + slot * 8);
    if (slot == 0) {                           // per-node coords + cycle pos-enc
      const float2 xy = ((const float2*)x)[b * 256 + node];
      const float th = 0.024543692605870074f * (float)node;   // 2*pi/256
      d.x = (int)pk2bf(xy.x, xy.y);
      d.y = (int)pk2bf(sinf(th), cosf(th));
      d.z = (int)pk2bf(sinf(2.f * th), cosf(2.f * th));
    }
    const int m = (node & 3) + 8 * ((node >> 2) & 3) + 4 * ((node >> 4) & 1);
    const int R = (node & ~31) | m;            // permuted LDS row
    *(i32x4*)(hbuf + R * 256 + ((slot ^ m) * 8)) = d;
  }

  // per-lane h'-write byte addresses (row within tile; r compile-time)
  int rowAddr[16];
  const int slotW = 4 * w + (c >> 3), offW = (c & 7) * 2;    // k-index = 32w+c
#pragma unroll
  for (int r = 0; r < 16; ++r) {
    const int row = (r & 3) + 8 * (r >> 2) + 4 * q;
    rowAddr[r] = row * 512 + ((slotW ^ row) * 16) + offW;
  }

  // B slices: wave w <-> group g=w>>1, tile t=w&1 (cols 32w..32w+31)
  const unsigned short* pL0 = packW + (w >> 1) * (9 * 1024) + (w & 1) * (9 * 512);
  const unsigned short* pL1 = packW + 36864 + (w >> 1) * (16 * 1024) + (w & 1) * (16 * 512);
  const unsigned short* pL2 = packW + 102400 + (w >> 1) * (16 * 1024) + (w & 1) * (16 * 512);
  bf16x8 Bf[16];
#pragma unroll
  for (int kt = 0; kt < 9; ++kt) Bf[kt] = *(const bf16x8*)(pL0 + kt * 512 + lane * 8);
  const float b30 = B0[w * 32 + c] * 0.33333334f;
  const float b31 = B1[w * 32 + c] * 0.33333334f;
  const float b32 = B2[w * 32 + c] * 0.33333334f;
  __syncthreads();   // h0 ready

  f32x16 accA[2], accB[2];
  float psum = 0.f, sv0, sv1, extP, extN;

  // ================= L0 =================
  fblock<9, 0, false, false, false>(hbuf, 0, 0, Bf, q, c, b30, accA, accA, 0.f, 0.f, rowAddr, psum);
  sv0 = accA[0][0]; sv1 = accA[0][1];                       // s~[0], s~[1] (q0)
  __syncthreads();
  fblock<9, 0, true, true, true>(hbuf, 1, 0, Bf, q, c, b30, accB, accA, 0.f, 0.f, rowAddr, psum);
  defer_last<0>(accA, accB[0][0], 0, q, hbuf, rowAddr, psum);       // node 63
  extP = xchg32(accA[1][15], 0.f, q);                               // s~[63] -> q0
  __syncthreads();
  fblock<9, 0, true, false, true>(hbuf, 2, 1, Bf, q, c, b30, accA, accB, extP, 0.f, rowAddr, psum);
  defer_last<0>(accB, accA[0][0], 1, q, hbuf, rowAddr, psum);       // node 127
  extP = xchg32(accB[1][15], 0.f, q);                               // s~[127]
  __syncthreads();
  fblock<9, 0, true, false, true>(hbuf, 3, 2, Bf, q, c, b30, accB, accA, extP, 0.f, rowAddr, psum);
  defer_last<0>(accA, accB[0][0], 2, q, hbuf, rowAddr, psum);       // node 191
  fix_node0<0>(accB[1][15], sv0, sv1, q, hbuf, rowAddr, psum);      // node 0
  extP = xchg32(accA[1][15], 0.f, q);                               // s~[191]
  extN = xchg32(0.f, sv0, q);                                       // s~[0] -> q1
#pragma unroll
  for (int kt = 0; kt < 16; ++kt) Bf[kt] = *(const bf16x8*)(pL1 + kt * 512 + lane * 8);
  __syncthreads();

  // ================= L1 =================
  fblock<16, 0, true, false, false>(hbuf, 0, 3, Bf, q, c, b31, accA, accB, extP, extN, rowAddr, psum);
  sv0 = accA[0][0]; sv1 = accA[0][1];
  __syncthreads();
  fblock<16, 1, true, true, true>(hbuf, 1, 0, Bf, q, c, b31, accB, accA, 0.f, 0.f, rowAddr, psum);
  defer_last<1>(accA, accB[0][0], 0, q, hbuf, rowAddr, psum);
  extP = xchg32(accA[1][15], 0.f, q);
  __syncthreads();
  fblock<16, 1, true, false, true>(hbuf, 2, 1, Bf, q, c, b31, accA, accB, extP, 0.f, rowAddr, psum);
  defer_last<1>(accB, accA[0][0], 1, q, hbuf, rowAddr, psum);
  extP = xchg32(accB[1][15], 0.f, q);
  __syncthreads();
  fblock<16, 1, true, false, true>(hbuf, 3, 2, Bf, q, c, b31, accB, accA, extP, 0.f, rowAddr, psum);
  defer_last<1>(accA, accB[0][0], 2, q, hbuf, rowAddr, psum);
  fix_node0<1>(accB[1][15], sv0, sv1, q, hbuf, rowAddr, psum);
  extP = xchg32(accA[1][15], 0.f, q);
  extN = xchg32(0.f, sv0, q);
#pragma unroll
  for (int kt = 0; kt < 16; ++kt) Bf[kt] = *(const bf16x8*)(pL2 + kt * 512 + lane * 8);
  __syncthreads();

  // ================= L2 (pool only; no LDS writes -> fewer barriers) =================
  fblock<16, 1, true, false, false>(hbuf, 0, 3, Bf, q, c, b32, accA, accB, extP, extN, rowAddr, psum);
  sv0 = accA[0][0]; sv1 = accA[0][1];
  __syncthreads();                              // epi(s3,L1) wrote rows 192..255
  fblock<16, 2, true, true, true>(hbuf, 1, 0, Bf, q, c, b32, accB, accA, 0.f, 0.f, rowAddr, psum);
  defer_last<2>(accA, accB[0][0], 0, q, hbuf, rowAddr, psum);
  extP = xchg32(accA[1][15], 0.f, q);
  fblock<16, 2, true, false, true>(hbuf, 2, 1, Bf, q, c, b32, accA, accB, extP, 0.f, rowAddr, psum);
  defer_last<2>(accB, accA[0][0], 1, q, hbuf, rowAddr, psum);
  extP = xchg32(accB[1][15], 0.f, q);
  fblock<16, 2, true, false, true>(hbuf, 3, 2, Bf, q, c, b32, accB, accA, extP, 0.f, rowAddr, psum);
  defer_last<2>(accA, accB[0][0], 2, q, hbuf, rowAddr, psum);
  fix_node0<2>(accB[1][15], sv0, sv1, q, hbuf, rowAddr, psum);
  extP = xchg32(accA[1][15], 0.f, q);
  extN = xchg32(0.f, sv0, q);
  epi_only<2>(accB, q, extP, extN, 3, hbuf, rowAddr, psum);

  const float s2 = psum + xchg32(psum, psum, q);
  if (q == 0) out[b * 256 + w * 32 + c] = s2 * (1.0f / 256.0f);
}

// ---------------- launch ----------------
extern "C" void kernel_launch(void* const* d_in, const int* in_sizes, int n_in,
                              void* d_out, int out_size, void* d_ws, size_t ws_size,
                              hipStream_t stream) {
  const float* x  = (const float*)d_in[0];
  const float* t  = (const float*)d_in[1];
  const float* tw = (const float*)d_in[2];
  const float* tb = (const float*)d_in[3];
  const float* W0 = (const float*)d_in[4];
  const float* b0 = (const float*)d_in[5];
  const float* W1 = (const float*)d_in[6];
  const float* b1 = (const float*)d_in[7];
  const float* W2 = (const float*)d_in[8];
  const float* b2 = (const float*)d_in[9];

  unsigned short* packW = (unsigned short*)d_ws;   // 167936 shorts
  float* out = (float*)d_out;

  pack_kernel<<<41, 512, 0, stream>>>(W0, W1, W2, packW);
  poly_kernel<<<1024, 512, 0, stream>>>(x, t, tw, tb, packW, b0, b1, b2, out);
}

// Round 7
// 176.315 us; speedup vs baseline: 2.0848x; 1.0569x over previous
//
#include <hip/hip_runtime.h>
#include <cstdint>

typedef __attribute__((ext_vector_type(8)))  short bf16x8;   // 8 x bf16 (4 VGPR)
typedef __attribute__((ext_vector_type(16))) float f32x16;   // MFMA 32x32 acc
typedef __attribute__((ext_vector_type(4)))  int   i32x4;

__device__ __forceinline__ unsigned short f2bf(float x) {    // RNE fp32->bf16
  unsigned u = __float_as_uint(x);
  u += 0x7fffu + ((u >> 16) & 1u);
  return (unsigned short)(u >> 16);
}
__device__ __forceinline__ unsigned pk2bf(float lo, float hi) {
#if defined(__has_builtin)
#if __has_builtin(__builtin_amdgcn_cvt_pk_bf16_f32)
  auto v = __builtin_amdgcn_cvt_pk_bf16_f32(lo, hi);
  unsigned u; __builtin_memcpy(&u, &v, 4); return u;
#else
  return ((unsigned)f2bf(hi) << 16) | (unsigned)f2bf(lo);
#endif
#else
  return ((unsigned)f2bf(hi) << 16) | (unsigned)f2bf(lo);
#endif
}
__device__ __forceinline__ float silu_f(float v) {
  return v * __builtin_amdgcn_rcpf(1.0f + __expf(-v));
}

// half-exchange without the LDS pipe: lanes 0-31 receive A from lane+32,
// lanes 32-63 receive B from lane-32  (== __shfl_xor(q ? A : B, 32)).
__device__ __forceinline__ float xchg32(float A, float B, int q) {
#if defined(__has_builtin)
#if __has_builtin(__builtin_amdgcn_permlane32_swap)
  auto r = __builtin_amdgcn_permlane32_swap(__float_as_uint(A), __float_as_uint(B),
                                            false, false);
  return __uint_as_float(q ? r[0] : r[1]);
#else
  return __shfl_xor(q ? A : B, 32);
#endif
#else
  return __shfl_xor(q ? A : B, 32);
#endif
}

// ---- pack W/3 into MFMA B-frag order via LDS transpose (coalesced R+W).
// 1/3 aggregation factor folded into the weights; bias folded into acc init.
// dest layout: [layer][g(64 cols)][t(32-col tile)][kt][lane][8], K0 padded 134->144.
__global__ void pack_kernel(const float* __restrict__ W0, const float* __restrict__ W1,
                            const float* __restrict__ W2,
                            unsigned short* __restrict__ packW) {
  __shared__ float ldsF[16][257];
  const int s = blockIdx.x, tid = threadIdx.x;
  const float* W; int KT, kmax, base, kt;
  if (s < 9)       { W = W0; KT = 9;  kmax = 134; base = 0;      kt = s; }
  else if (s < 25) { W = W1; KT = 16; kmax = 256; base = 36864;  kt = s - 9; }
  else             { W = W2; KT = 16; kmax = 256; base = 102400; kt = s - 25; }
  const int k0 = kt * 16;
#pragma unroll
  for (int i = 0; i < 8; ++i) {                 // 512 thr x 8 = 16 x 256 floats
    const int idx = i * 512 + tid;
    const int kl = idx >> 8, col = idx & 255;
    const int kg = k0 + kl;
    ldsF[kl][col] = (kg < kmax) ? W[kg * 256 + col] * 0.33333334f : 0.0f;
  }
  __syncthreads();
  const int g = tid >> 7, t = (tid >> 6) & 1, lane = tid & 63;
  const int col = g * 64 + t * 32 + (lane & 31);
  const int kb = 8 * (lane >> 5);
  unsigned u0 = pk2bf(ldsF[kb + 0][col], ldsF[kb + 1][col]);
  unsigned u1 = pk2bf(ldsF[kb + 2][col], ldsF[kb + 3][col]);
  unsigned u2 = pk2bf(ldsF[kb + 4][col], ldsF[kb + 5][col]);
  unsigned u3 = pk2bf(ldsF[kb + 6][col], ldsF[kb + 7][col]);
  unsigned short* dst = packW + base + g * (KT * 1024) + t * (KT * 512) + kt * 512 + lane * 8;
  i32x4 v = { (int)u0, (int)u1, (int)u2, (int)u3 };
  *(i32x4*)dst = v;
}

// ======================================================================
// Wave w owns ALL 256 nodes x cols [32w,32w+32). Node->A-row permutation puts
// 16 CONSECUTIVE nodes in each lane's acc regs: node 32nt + 16q + r.
// s~[n] = (h W/3)[n] + bias/3 (bias via acc init) => y[n] = silu(s~[n-1]+s~[n]+s~[n+1]).
// L0 temb-fold: temb is node-invariant -> tW = temb @ W0/3 computed ONCE per
// wave (9 MFMAs, broadcast A from tmpl; all C rows equal -> scalar C[0]);
// L0 acc init = tW + b0/3, per-node L0 GEMM K=16 (coords+pe only, 1 kt).
// 4 subs of 2 tiles, ping-pong acc, kloop interleaved 1:1 with prev-sub epilogue,
// explicit depth-1 A-frag prefetch. Boundary exchange via v_permlane32_swap.
// h' stores via v_cvt_pk_bf16_f32 pairs. h[256][256] bf16 in 128KB LDS,
// 16B-slot XOR swizzle (slot ^= row&31). B slice resident in 64 VGPRs.
// ======================================================================

// one epilogue PAIR p (values r=2(p&7), +1 of tile t=p>>3); mid-sum shared
template <int ELAYER, bool DF, bool DL>
__device__ __forceinline__ void epi_pair(
    const int p, const f32x16* accEpi, const int q,
    const float recvI0, const float recvI1, const float recvX,
    const float extP, const float extN,
    const int epiSub, unsigned short* __restrict__ hbuf,
    const int* rowAddr, float& psum) {
  const int t = p >> 3, rp = (p & 7) * 2;
  const float mid = accEpi[t][rp] + accEpi[t][rp + 1];
  float prev, next;
  if (rp > 0) prev = accEpi[t][rp - 1];
  else        prev = q ? (t ? recvI1 : recvI0) : (t ? recvX : extP);
  if (rp < 14) next = accEpi[t][rp + 2];
  else         next = q ? (t ? extN : recvX) : (t ? recvI1 : recvI0);
  const float y0 = silu_f(prev + mid);
  const float y1 = silu_f(mid + next);
  const bool c0 = !(DF && t == 0 && rp == 0 && q == 0);
  const bool c1 = !(DL && t == 1 && rp == 14 && q == 1);
  if constexpr (ELAYER == 2) {
    if (c0) psum += y0;
    if (c1) psum += y1;
  } else {
    const unsigned u = pk2bf(y0, y1);
    char* bp = (char*)hbuf + (2 * epiSub + t) * 16384;
    if (c0) *(unsigned short*)(bp + rowAddr[rp])     = (unsigned short)u;
    if (c1) *(unsigned short*)(bp + rowAddr[rp + 1]) = (unsigned short)(u >> 16);
  }
}

// fused block: kloop over 2 tiles of readSub (acc init = bias-ish scalar),
// depth-1 A prefetch, interleaved with epilogue pairs of epiSub (prev sub).
template <int KT, int ELAYER, bool DOEPI, bool DF, bool DL>
__device__ __forceinline__ void fblock(
    unsigned short* __restrict__ hbuf, const int readSub, const int epiSub,
    const bf16x8* Bf, const int q, const int c, const float bias3,
    f32x16* accOut, const f32x16* accEpi,
    const float extP, const float extN,
    const int* rowAddr, float& psum) {
  float recvI0 = 0.f, recvI1 = 0.f, recvX = 0.f;
  if constexpr (DOEPI) {
    recvI0 = xchg32(accEpi[0][0],  accEpi[0][15], q);
    recvI1 = xchg32(accEpi[1][0],  accEpi[1][15], q);
    recvX  = xchg32(accEpi[0][15], accEpi[1][0],  q);
  }
#pragma unroll
  for (int t2 = 0; t2 < 2; ++t2)
#pragma unroll
    for (int j = 0; j < 16; ++j) accOut[t2][j] = bias3;
  const unsigned short* rb = hbuf + readSub * 16384 + c * 256;
  bf16x8 a0 = *(const bf16x8*)(rb + ((q ^ c) * 8));
  bf16x8 a1 = *(const bf16x8*)(rb + ((q ^ c) * 8) + 8192);
#pragma unroll
  for (int kt = 0; kt < KT; ++kt) {
    const bf16x8 u0 = a0, u1 = a1;
    if (kt + 1 < KT) {                          // depth-1 prefetch
      const unsigned short* nb = rb + (((2 * (kt + 1) + q) ^ c) * 8);
      a0 = *(const bf16x8*)(nb);
      a1 = *(const bf16x8*)(nb + 8192);
    }
    accOut[0] = __builtin_amdgcn_mfma_f32_32x32x16_bf16(u0, Bf[kt], accOut[0], 0, 0, 0);
    accOut[1] = __builtin_amdgcn_mfma_f32_32x32x16_bf16(u1, Bf[kt], accOut[1], 0, 0, 0);
    if constexpr (DOEPI) {
#pragma unroll
      for (int p = (kt * 16) / KT; p < ((kt + 1) * 16) / KT; ++p)
        epi_pair<ELAYER, DF, DL>(p, accEpi, q, recvI0, recvI1, recvX, extP, extN,
                                 epiSub, hbuf, rowAddr, psum);
    }
  }
}

template <int ELAYER>
__device__ __forceinline__ void epi_only(
    const f32x16* accEpi, const int q, const float extP, const float extN,
    const int epiSub, unsigned short* __restrict__ hbuf,
    const int* rowAddr, float& psum) {
  const float recvI0 = xchg32(accEpi[0][0],  accEpi[0][15], q);
  const float recvI1 = xchg32(accEpi[1][0],  accEpi[1][15], q);
  const float recvX  = xchg32(accEpi[0][15], accEpi[1][0],  q);
#pragma unroll
  for (int p = 0; p < 16; ++p)
    epi_pair<ELAYER, false, false>(p, accEpi, q, recvI0, recvI1, recvX, extP, extN,
                                   epiSub, hbuf, rowAddr, psum);
}

// node 64e+63 (q1 lanes): prev/cur in accEpi[1][14..15], next = new sub's node 64e+64
template <int ELAYER>
__device__ __forceinline__ void defer_last(
    const f32x16* accEpi, const float accNew00, const int epiSub,
    const int q, unsigned short* __restrict__ hbuf,
    const int* rowAddr, float& psum) {
  const float recv = xchg32(0.f, accNew00, q);   // q1 <- s~[64e+64]
  const float y = silu_f(accEpi[1][14] + accEpi[1][15] + recv);
  if (q) {
    if constexpr (ELAYER == 2) psum += y;
    else *(unsigned short*)((char*)hbuf + (2 * epiSub + 1) * 16384 + rowAddr[15]) = f2bf(y);
  }
}

// node 0 (q0 lanes): prev = s~[255], cur/next = saved s~[0], s~[1]
template <int ELAYER>
__device__ __forceinline__ void fix_node0(
    const float s255src, const float sv0, const float sv1,
    const int q, unsigned short* __restrict__ hbuf,
    const int* rowAddr, float& psum) {
  const float recv = xchg32(s255src, 0.f, q);    // q0 <- s~[255]
  const float y = silu_f(recv + sv0 + sv1);
  if (!q) {
    if constexpr (ELAYER == 2) psum += y;
    else *(unsigned short*)((char*)hbuf + rowAddr[0]) = f2bf(y);
  }
}

// ---------------- main fused kernel: 1 block = 1 graph, 8 waves x 32 cols ----------
__global__ __launch_bounds__(512, 1) void poly_kernel(
    const float* __restrict__ x, const float* __restrict__ t,
    const float* __restrict__ tw, const float* __restrict__ tb,
    const unsigned short* __restrict__ packW,
    const float* __restrict__ B0, const float* __restrict__ B1,
    const float* __restrict__ B2, float* __restrict__ out) {
  __shared__ __align__(16) unsigned short hbuf[65536];  // 128 KiB: h[row][256] bf16, swizzled
  __shared__ __align__(16) unsigned short tmpl[160];    // h0 row template (temb + pads)

  const int tid = threadIdx.x;
  const int w = tid >> 6, lane = tid & 63, q = lane >> 5, c = lane & 31;
  const int b = blockIdx.x;

  // ---- fused time MLP: temb = silu(sinemb(t[b]) @ tw + tb) ----
  {
    float* scr = (float*)hbuf;        // reuse h as f32 scratch (overwritten later)
    if (tid < 128) {
      const float tv = t[b];
      const int i = tid & 63;
      const float f = expf(-0.14619588396823767f * (float)i);  // log(1e4)/63
      const float ang = tv * f;
      scr[tid] = (tid < 64) ? sinf(ang) : cosf(ang);
    }
    __syncthreads();
    {
      const int j = tid & 127, p = tid >> 7;   // 4-way k-split over the block
      float a = 0.f;
#pragma unroll 8
      for (int kk = 0; kk < 32; ++kk) a += scr[p * 32 + kk] * tw[(p * 32 + kk) * 128 + j];
      scr[128 + tid] = a;
    }
    __syncthreads();
    if (tid < 128) {
      const float a = tb[tid] + scr[128 + tid] + scr[256 + tid] + scr[384 + tid] + scr[512 + tid];
      tmpl[6 + tid] = f2bf(silu_f(a));
      if (tid < 6)  tmpl[tid] = 0;
      if (tid < 26) tmpl[134 + tid] = 0;   // pad k 134..159 = 0
    }
    __syncthreads();
  }

  // B slices: wave w <-> group g=w>>1, tile t=w&1 (cols 32w..32w+31)
  const unsigned short* pL0 = packW + (w >> 1) * (9 * 1024) + (w & 1) * (9 * 512);
  const unsigned short* pL1 = packW + 36864 + (w >> 1) * (16 * 1024) + (w & 1) * (16 * 512);
  const unsigned short* pL2 = packW + 102400 + (w >> 1) * (16 * 1024) + (w & 1) * (16 * 512);
  bf16x8 Bf[16];
#pragma unroll
  for (int kt = 0; kt < 9; ++kt) Bf[kt] = *(const bf16x8*)(pL0 + kt * 512 + lane * 8);
  const float b30 = B0[w * 32 + c] * 0.33333334f;
  const float b31 = B1[w * 32 + c] * 0.33333334f;
  const float b32 = B2[w * 32 + c] * 0.33333334f;

  // ---- tW fold: node-invariant part of L0 (temb @ W0/3), once per wave ----
  // A rows all = tmpl (zeros in k0..5) -> every C element = tW[col]; take C[0].
  float initL0;
  {
    f32x16 Ct;
#pragma unroll
    for (int j = 0; j < 16; ++j) Ct[j] = 0.f;
#pragma unroll
    for (int kt = 0; kt < 9; ++kt) {
      const bf16x8 at = *(const bf16x8*)(tmpl + kt * 16 + q * 8);
      Ct = __builtin_amdgcn_mfma_f32_32x32x16_bf16(at, Bf[kt], Ct, 0, 0, 0);
    }
    initL0 = Ct[0] + b30;
  }

  // ---- build h0 (features only): slots 0,1 per node = [xy, pe, 0-pad] ----
  {
    const int node = tid >> 1, sl = tid & 1;
    i32x4 d = {0, 0, 0, 0};
    if (sl == 0) {
      const float2 xy = ((const float2*)x)[b * 256 + node];
      const float th = 0.024543692605870074f * (float)node;   // 2*pi/256
      d.x = (int)pk2bf(xy.x, xy.y);
      d.y = (int)pk2bf(sinf(th), cosf(th));
      d.z = (int)pk2bf(sinf(2.f * th), cosf(2.f * th));
    }
    const int m = (node & 3) + 8 * ((node >> 2) & 3) + 4 * ((node >> 4) & 1);
    const int R = (node & ~31) | m;            // permuted LDS row
    *(i32x4*)(hbuf + R * 256 + ((sl ^ m) * 8)) = d;
  }

  // per-lane h'-write byte addresses (row within tile; r compile-time)
  int rowAddr[16];
  const int slotW = 4 * w + (c >> 3), offW = (c & 7) * 2;    // k-index = 32w+c
#pragma unroll
  for (int r = 0; r < 16; ++r) {
    const int row = (r & 3) + 8 * (r >> 2) + 4 * q;
    rowAddr[r] = row * 512 + ((slotW ^ row) * 16) + offW;
  }
  __syncthreads();   // h0 ready

  f32x16 accA[2], accB[2];
  float psum = 0.f, sv0, sv1, extP, extN;

  // ================= L0 (K=16: coords+pe; temb folded into initL0) =================
  fblock<1, 0, false, false, false>(hbuf, 0, 0, Bf, q, c, initL0, accA, accA, 0.f, 0.f, rowAddr, psum);
  sv0 = accA[0][0]; sv1 = accA[0][1];                       // s~[0], s~[1] (q0)
  __syncthreads();
  fblock<1, 0, true, true, true>(hbuf, 1, 0, Bf, q, c, initL0, accB, accA, 0.f, 0.f, rowAddr, psum);
  defer_last<0>(accA, accB[0][0], 0, q, hbuf, rowAddr, psum);       // node 63
  extP = xchg32(accA[1][15], 0.f, q);                               // s~[63] -> q0
  __syncthreads();
  fblock<1, 0, true, false, true>(hbuf, 2, 1, Bf, q, c, initL0, accA, accB, extP, 0.f, rowAddr, psum);
  defer_last<0>(accB, accA[0][0], 1, q, hbuf, rowAddr, psum);       // node 127
  extP = xchg32(accB[1][15], 0.f, q);                               // s~[127]
  __syncthreads();
  fblock<1, 0, true, false, true>(hbuf, 3, 2, Bf, q, c, initL0, accB, accA, extP, 0.f, rowAddr, psum);
  defer_last<0>(accA, accB[0][0], 2, q, hbuf, rowAddr, psum);       // node 191
  fix_node0<0>(accB[1][15], sv0, sv1, q, hbuf, rowAddr, psum);      // node 0
  extP = xchg32(accA[1][15], 0.f, q);                               // s~[191]
  extN = xchg32(0.f, sv0, q);                                       // s~[0] -> q1
#pragma unroll
  for (int kt = 0; kt < 16; ++kt) Bf[kt] = *(const bf16x8*)(pL1 + kt * 512 + lane * 8);
  __syncthreads();

  // ================= L1 =================
  fblock<16, 0, true, false, false>(hbuf, 0, 3, Bf, q, c, b31, accA, accB, extP, extN, rowAddr, psum);
  sv0 = accA[0][0]; sv1 = accA[0][1];
  __syncthreads();
  fblock<16, 1, true, true, true>(hbuf, 1, 0, Bf, q, c, b31, accB, accA, 0.f, 0.f, rowAddr, psum);
  defer_last<1>(accA, accB[0][0], 0, q, hbuf, rowAddr, psum);
  extP = xchg32(accA[1][15], 0.f, q);
  __syncthreads();
  fblock<16, 1, true, false, true>(hbuf, 2, 1, Bf, q, c, b31, accA, accB, extP, 0.f, rowAddr, psum);
  defer_last<1>(accB, accA[0][0], 1, q, hbuf, rowAddr, psum);
  extP = xchg32(accB[1][15], 0.f, q);
  __syncthreads();
  fblock<16, 1, true, false, true>(hbuf, 3, 2, Bf, q, c, b31, accB, accA, extP, 0.f, rowAddr, psum);
  defer_last<1>(accA, accB[0][0], 2, q, hbuf, rowAddr, psum);
  fix_node0<1>(accB[1][15], sv0, sv1, q, hbuf, rowAddr, psum);
  extP = xchg32(accA[1][15], 0.f, q);
  extN = xchg32(0.f, sv0, q);
#pragma unroll
  for (int kt = 0; kt < 16; ++kt) Bf[kt] = *(const bf16x8*)(pL2 + kt * 512 + lane * 8);
  __syncthreads();

  // ================= L2 (pool only; no LDS writes -> fewer barriers) =================
  fblock<16, 1, true, false, false>(hbuf, 0, 3, Bf, q, c, b32, accA, accB, extP, extN, rowAddr, psum);
  sv0 = accA[0][0]; sv1 = accA[0][1];
  __syncthreads();                              // epi(s3,L1) wrote rows 192..255
  fblock<16, 2, true, true, true>(hbuf, 1, 0, Bf, q, c, b32, accB, accA, 0.f, 0.f, rowAddr, psum);
  defer_last<2>(accA, accB[0][0], 0, q, hbuf, rowAddr, psum);
  extP = xchg32(accA[1][15], 0.f, q);
  fblock<16, 2, true, false, true>(hbuf, 2, 1, Bf, q, c, b32, accA, accB, extP, 0.f, rowAddr, psum);
  defer_last<2>(accB, accA[0][0], 1, q, hbuf, rowAddr, psum);
  extP = xchg32(accB[1][15], 0.f, q);
  fblock<16, 2, true, false, true>(hbuf, 3, 2, Bf, q, c, b32, accB, accA, extP, 0.f, rowAddr, psum);
  defer_last<2>(accA, accB[0][0], 2, q, hbuf, rowAddr, psum);
  fix_node0<2>(accB[1][15], sv0, sv1, q, hbuf, rowAddr, psum);
  extP = xchg32(accA[1][15], 0.f, q);
  extN = xchg32(0.f, sv0, q);
  epi_only<2>(accB, q, extP, extN, 3, hbuf, rowAddr, psum);

  const float s2 = psum + xchg32(psum, psum, q);
  if (q == 0) out[b * 256 + w * 32 + c] = s2 * (1.0f / 256.0f);
}

// ---------------- launch ----------------
extern "C" void kernel_launch(void* const* d_in, const int* in_sizes, int n_in,
                              void* d_out, int out_size, void* d_ws, size_t ws_size,
                              hipStream_t stream) {
  const float* x  = (const float*)d_in[0];
  const float* t  = (const float*)d_in[1];
  const float* tw = (const float*)d_in[2];
  const float* tb = (const float*)d_in[3];
  const float* W0 = (const float*)d_in[4];
  const float* b0 = (const float*)d_in[5];
  const float* W1 = (const float*)d_in[6];
  const float* b1 = (const float*)d_in[7];
  const float* W2 = (const float*)d_in[8];
  const float* b2 = (const float*)d_in[9];

  unsigned short* packW = (unsigned short*)d_ws;   // 167936 shorts
  float* out = (float*)d_out;

  pack_kernel<<<41, 512, 0, stream>>>(W0, W1, W2, packW);
  poly_kernel<<<1024, 512, 0, stream>>>(x, t, tw, tb, packW, b0, b1, b2, out);
}